// Round 8
// baseline (526.683 us; speedup 1.0000x reference)
//
#include <hip/hip_runtime.h>
#include <hip/hip_bf16.h>

typedef __attribute__((ext_vector_type(8))) short bf16x8;
typedef __attribute__((ext_vector_type(4))) float f32x4;

#define BB 4
#define TT 16
#define NT0 12
#define LL 64
#define CC 512
#define HH 8
#define HD 64
#define NQ (NT0*LL)       // 768 queries per batch
#define NCTX (TT*LL)      // 1024 cross keys per batch

#define GPTR(x) ((__attribute__((address_space(1))) void*)(x))
#define SPTR(x) ((__attribute__((address_space(3))) void*)(x))
// waitcnt imm: vmcnt(n) in [3:0] (n<=15 here), lgkmcnt=15 (no wait), expcnt=7 (no wait)
#define VMCNT(n) (((n) & 15) | (7u << 4) | (0xFu << 8))

__device__ __forceinline__ float bf2f(ushort u) {
  union { unsigned int i; float f; } x; x.i = ((unsigned int)u) << 16; return x.f;
}
__device__ __forceinline__ ushort f2bf(float f) {
  union { float f; unsigned int i; } x; x.f = f;
  unsigned int r = x.i + 0x7fffu + ((x.i >> 16) & 1u);  // RNE
  return (ushort)(r >> 16);
}

// ---------------------------------------------------------------------------
// R18: manual grid barrier (plain launch; no cooperative API -> graph-capture
// safe). 768 blocks @ 48KB LDS + launch_bounds(256,3) = 3 blocks/CU exactly,
// so all blocks are co-resident by construction. Release: __syncthreads
// drains each thread's stores to L2 (compiler emits s_waitcnt vmcnt(0)), then
// leader's __threadfence_system (buffer_wbl2) pushes the XCD's dirty L2 to
// MALL before arrive. Acquire: relaxed spin on gen, then every thread fences
// (buffer_inv) after the sync.
// ---------------------------------------------------------------------------
__device__ __forceinline__ void grid_bar(int* __restrict__ bar, int gen) {
  __syncthreads();
  if (threadIdx.x == 0) {
    __threadfence_system();
    int old = __hip_atomic_fetch_add(&bar[0], 1, __ATOMIC_ACQ_REL,
                                     __HIP_MEMORY_SCOPE_SYSTEM);
    if (old == 767) {
      __hip_atomic_store(&bar[0], 0, __ATOMIC_RELAXED, __HIP_MEMORY_SCOPE_SYSTEM);
      __threadfence_system();
      __hip_atomic_store(&bar[1], gen, __ATOMIC_RELEASE, __HIP_MEMORY_SCOPE_SYSTEM);
    } else {
      while (__hip_atomic_load(&bar[1], __ATOMIC_RELAXED,
                               __HIP_MEMORY_SCOPE_SYSTEM) < gen)
        __builtin_amdgcn_s_sleep(4);
    }
  }
  __syncthreads();
  __threadfence_system();   // acquire side for every thread
}

// ---------------------------------------------------------------------------
// MTxNTW-tile GEMM block body, BK=32, TRIPLE-BUFFER depth-2 (R10-proven).
// R14: 128x64 tiles regress. R15: work-stealing regresses. 128x128 stands.
// ---------------------------------------------------------------------------
template<int MT, int NTW>
__device__ __forceinline__ void gemm_mac(const ushort* __restrict__ A,
                                         const ushort* __restrict__ W,
                                         int mt, int nt, ushort* lds,
                                         f32x4* acc) {
  constexpr int ASZ = MT * 32;         // A ushorts per buf
  constexpr int WSZ = NTW * 32;        // W ushorts per buf
  constexpr int BUF = ASZ + WSZ;       // buf stride in ushorts
  constexpr int L   = (MT == 128 ? 2 : 1) + (NTW == 128 ? 2 : 1);

  int t = threadIdx.x;
  int pa0 = t, pa1 = t + 256;
  int ra0 = pa0 >> 2, ra1 = pa1 >> 2;
  int ca0 = (pa0 & 3) ^ ((ra0 >> 1) & 3);
  int ca1 = (pa1 & 3) ^ ((ra1 >> 1) & 3);
  const ushort* ga0 = A + (size_t)(mt * MT + ra0) * 512 + ca0 * 8;
  const ushort* ga1 = A + (size_t)(mt * MT + ra1) * 512 + ca1 * 8;
  const ushort* gw0 = W + (size_t)(nt * NTW + ra0) * 512 + ca0 * 8;
  const ushort* gw1 = W + (size_t)(nt * NTW + ra1) * 512 + ca1 * 8;

  int lane = t & 63, l15 = lane & 15, kg = lane >> 4;
  int wv = t >> 6;
  int mh = (wv >> 1) * (MT / 2), nh = (wv & 1) * (NTW / 2);
  int swz = kg ^ ((l15 >> 1) & 3);
  int faoff = (mh + l15) * 32 + swz * 8;
  int fwoff = (nh + l15) * 32 + swz * 8;

  auto stage = [&](int ks, int bb) {
    int ko = ks * 32;
    __builtin_amdgcn_global_load_lds(GPTR(ga0 + ko), SPTR(lds + bb + pa0 * 8), 16, 0, 0);
    if (MT == 128)
      __builtin_amdgcn_global_load_lds(GPTR(ga1 + ko), SPTR(lds + bb + pa1 * 8), 16, 0, 0);
    __builtin_amdgcn_global_load_lds(GPTR(gw0 + ko), SPTR(lds + bb + ASZ + pa0 * 8), 16, 0, 0);
    if (NTW == 128)
      __builtin_amdgcn_global_load_lds(GPTR(gw1 + ko), SPTR(lds + bb + ASZ + pa1 * 8), 16, 0, 0);
  };

  stage(0, 0);
  stage(1, BUF);

#pragma unroll
  for (int ks = 0; ks < 16; ++ks) {
    int cur = (ks % 3) * BUF;
    if (ks < 14) {
      stage(ks + 2, ((ks + 2) % 3) * BUF);
      __builtin_amdgcn_s_waitcnt(VMCNT(2 * L));
    } else if (ks == 14) {
      __builtin_amdgcn_s_waitcnt(VMCNT(L));
    } else {
      __builtin_amdgcn_s_waitcnt(VMCNT(0));
    }
    asm volatile("" ::: "memory");
    __builtin_amdgcn_s_barrier();
    asm volatile("" ::: "memory");

    const ushort* fa = lds + cur + faoff;
    const ushort* fw = lds + cur + ASZ + fwoff;
    bf16x8 af[MT / 32], wf[NTW / 32];
#pragma unroll
    for (int i = 0; i < MT / 32; ++i) af[i] = *(const bf16x8*)(fa + i * 512);
#pragma unroll
    for (int i = 0; i < NTW / 32; ++i) wf[i] = *(const bf16x8*)(fw + i * 512);
#pragma unroll
    for (int mi = 0; mi < MT / 32; ++mi)
#pragma unroll
      for (int ni = 0; ni < NTW / 32; ++ni)
        acc[mi * (NTW / 32) + ni] =
            __builtin_amdgcn_mfma_f32_16x16x32_bf16(af[mi], wf[ni], acc[mi * (NTW / 32) + ni], 0, 0, 0);

    asm volatile("" ::: "memory");
    __builtin_amdgcn_s_barrier();
    asm volatile("" ::: "memory");
  }
}

// OUTMODE 0: C bf16 row-major [*,N]. 1: CT bf16 transposed CT[col*TM+row]
// (CT may be pre-offset). 2: Cf f32 row-major + bias.
template<int MT, int NTW, int OUTMODE>
__device__ __forceinline__ void gemm_body(const ushort* __restrict__ A,
                                          const ushort* __restrict__ W,
                                          ushort* __restrict__ C,
                                          ushort* __restrict__ CT,
                                          float* __restrict__ Cf,
                                          const float* __restrict__ bias,
                                          int mt, int nt, int N, long TM,
                                          ushort* lds) {
  f32x4 acc[(MT / 32) * (NTW / 32)];
#pragma unroll
  for (int i = 0; i < (MT / 32) * (NTW / 32); ++i) acc[i] = (f32x4){0, 0, 0, 0};
  gemm_mac<MT, NTW>(A, W, mt, nt, lds, acc);

  int lane = threadIdx.x & 63, l15 = lane & 15, kg = lane >> 4;
  int wv = threadIdx.x >> 6;
  int Rw = mt * MT + (wv >> 1) * (MT / 2);
  int Cw = nt * NTW + (wv & 1) * (NTW / 2);
#pragma unroll
  for (int mi = 0; mi < MT / 32; ++mi) {
    int row = Rw + mi * 16 + kg * 4;
#pragma unroll
    for (int ni = 0; ni < NTW / 32; ++ni) {
      f32x4 v = acc[mi * (NTW / 32) + ni];
      int col = Cw + ni * 16 + l15;
      if (OUTMODE == 0) {
#pragma unroll
        for (int r = 0; r < 4; ++r) C[(size_t)(row + r) * N + col] = f2bf(v[r]);
      } else if (OUTMODE == 1) {
        ushort4 o = { f2bf(v[0]), f2bf(v[1]), f2bf(v[2]), f2bf(v[3]) };
        *(ushort4*)(CT + (long)col * TM + row) = o;
      } else {
        float bv = bias[col];
#pragma unroll
        for (int r = 0; r < 4; ++r) Cf[(size_t)(row + r) * N + col] = v[r] + bv;
      }
    }
  }
}

// One attention tile for a 32-query wave [R11-proven; R16 pad-76 strips].
__device__ __forceinline__ void attn_tile32(const ushort* __restrict__ kbase, int kstr,
                                            const ushort* __restrict__ vtb, int vtN,
                                            bf16x8 qa0, bf16x8 qa1,
                                            bf16x8 qb0, bf16x8 qb1,
                                            int l15, int kg,
                                            ushort* __restrict__ Pt,
                                            f32x4 (*acc)[4], float* Lacc) {
  f32x4 s[2][4];
#pragma unroll
  for (int st = 0; st < 4; ++st) {
    const ushort* kp = kbase + (size_t)(st * 16 + l15) * kstr + kg * 8;
    bf16x8 k0 = *(const bf16x8*)kp;
    bf16x8 k1 = *(const bf16x8*)(kp + 32);
    f32x4 z0 = {0, 0, 0, 0}, z1 = {0, 0, 0, 0};
    z0 = __builtin_amdgcn_mfma_f32_16x16x32_bf16(k0, qa0, z0, 0, 0, 0);
    z0 = __builtin_amdgcn_mfma_f32_16x16x32_bf16(k1, qa1, z0, 0, 0, 0);
    z1 = __builtin_amdgcn_mfma_f32_16x16x32_bf16(k0, qb0, z1, 0, 0, 0);
    z1 = __builtin_amdgcn_mfma_f32_16x16x32_bf16(k1, qb1, z1, 0, 0, 0);
    s[0][st] = z0;
    s[1][st] = z1;
  }
#pragma unroll
  for (int qf = 0; qf < 2; ++qf) {
#pragma unroll
    for (int st = 0; st < 4; ++st) {
      float p0 = __builtin_exp2f(fmaf(s[qf][st][0], 0.18033688f, -23.0831206f));
      float p1 = __builtin_exp2f(fmaf(s[qf][st][1], 0.18033688f, -23.0831206f));
      float p2 = __builtin_exp2f(fmaf(s[qf][st][2], 0.18033688f, -23.0831206f));
      float p3 = __builtin_exp2f(fmaf(s[qf][st][3], 0.18033688f, -23.0831206f));
      Lacc[qf] += (p0 + p1) + (p2 + p3);
      ushort4 pk = { f2bf(p0), f2bf(p1), f2bf(p2), f2bf(p3) };
      *(ushort4*)(Pt + qf * 1216 + l15 * 76 + st * 16 + kg * 4) = pk;
    }
  }
#pragma unroll
  for (int kc = 0; kc < 2; ++kc) {
    bf16x8 pb0 = *(const bf16x8*)(Pt + l15 * 76 + kc * 32 + kg * 8);
    bf16x8 pb1 = *(const bf16x8*)(Pt + 1216 + l15 * 76 + kc * 32 + kg * 8);
#pragma unroll
    for (int d = 0; d < 4; ++d) {
      const ushort* vp = vtb + (size_t)(d * 16 + l15) * vtN + kc * 32 + kg * 8;
      bf16x8 vf = *(const bf16x8*)vp;
      acc[0][d] = __builtin_amdgcn_mfma_f32_16x16x32_bf16(vf, pb0, acc[0][d], 0, 0, 0);
      acc[1][d] = __builtin_amdgcn_mfma_f32_16x16x32_bf16(vf, pb1, acc[1][d], 0, 0, 0);
    }
  }
}

// ---------------------------------------------------------------------------
// R18: single fused kernel, 768 blocks x 256 threads, 48 KB LDS union, plain
// launch + manual grid barrier. Phase bodies byte-identical to R16 kernels.
// ---------------------------------------------------------------------------
__global__ __launch_bounds__(256, 3) void fused_all(
    const float* __restrict__ w0, const float* __restrict__ w1,
    const float* __restrict__ w2, const float* __restrict__ w3,
    const float* __restrict__ x,  const float* __restrict__ xc,
    const float* __restrict__ dxc, const int* __restrict__ ctx_mask,
    ushort* __restrict__ ws, const float* __restrict__ proj_b,
    float* __restrict__ out, int* __restrict__ bar) {
  __shared__ ushort lds[24576];   // 48 KB, reused by every phase

  ushort* qkvwb  = ws;                    //  786432
  ushort* kwb    = ws + 786432;           //  262144
  ushort* vwb    = ws + 1048576;          //  262144
  ushort* pwb    = ws + 1310720;          //  262144
  ushort* xb     = ws + 1572864;          // 3072x512
  ushort* xcb    = ws + 3145728;          // 4096x512
  ushort* dxb    = ws + 5242880;          // 4096x512
  ushort* qkv    = ws + 7340032;          // 3072x1536
  ushort* kctx   = ws + 12058624;         // 4096x512
  ushort* vctxT  = ws + 14155776;         // 512x4096
  ushort* vselfT = ws + 16252928;         // 512x3072
  ushort* aout   = ws + 17825792;         // 3072x512

  // ---- phase 1: cvt f32 -> bf16 (grid-stride; masked ctx frames skipped) ----
  for (long i = (long)blockIdx.x * 256 + threadIdx.x; i < 1835008; i += 196608) {
    const float* src; long off;
    if (i < 196608)       { src = w0;  off = 0; }
    else if (i < 262144)  { src = w1;  off = 196608; }
    else if (i < 327680)  { src = w2;  off = 262144; }
    else if (i < 393216)  { src = w3;  off = 327680; }
    else if (i < 786432)  { src = x;   off = 393216; }
    else if (i < 1310720) {
      int r = (int)((i - 786432) >> 7);            // row in (4096, 512)
      if (ctx_mask[(r >> 10) * TT + ((r >> 6) & 15)] == 0) continue;
      src = xc;  off = 786432;
    } else {
      int r = (int)((i - 1310720) >> 7);
      if (ctx_mask[(r >> 10) * TT + ((r >> 6) & 15)] == 0) continue;
      src = dxc; off = 1310720;
    }
    f32x4 v = *(const f32x4*)(src + (i - off) * 4);
    ushort4 o = { f2bf(v[0]), f2bf(v[1]), f2bf(v[2]), f2bf(v[3]) };
    *(ushort4*)(ws + i * 4) = o;
  }
  grid_bar(bar, 1);

  // ---- phase 2: fused input GEMMs (items 0..543; R13-proven decode) ----
  {
    int blk = blockIdx.x;
    if (blk < 288) {
      int mt = blk % 24, nt = blk / 24;
      if (nt < 8)
        gemm_body<128, 128, 0>(xb, qkvwb, qkv, nullptr, nullptr, nullptr, mt, nt, 1536, 0, lds);
      else
        gemm_body<128, 128, 1>(xb, qkvwb, nullptr, vselfT - (size_t)1024 * 3072, nullptr, nullptr,
                               mt, nt, 1536, 3072, lds);
    } else if (blk < 416) {
      int r = blk - 288;
      int mt = r % 32, nt = r / 32;
      int bb = mt >> 3, f0 = (mt & 7) << 1;
      if (ctx_mask[bb * TT + f0] != 0 || ctx_mask[bb * TT + f0 + 1] != 0)
        gemm_body<128, 128, 0>(dxb, kwb, kctx, nullptr, nullptr, nullptr, mt, nt, 512, 0, lds);
    } else if (blk < 544) {
      int r = blk - 416;
      int mt = r % 32, nt = r / 32;
      int bb = mt >> 3, f0 = (mt & 7) << 1;
      if (ctx_mask[bb * TT + f0] != 0 || ctx_mask[bb * TT + f0 + 1] != 0)
        gemm_body<128, 128, 1>(xcb, vwb, nullptr, vctxT, nullptr, nullptr, mt, nt, 512, 4096, lds);
    }
  }
  grid_bar(bar, 2);

  // ---- phase 3: flash attention (item = blockIdx.x, 768 exact; R13/R16) ----
  {
    float* smem = (float*)lds;
    int blk = blockIdx.x;              // h + 8*(qg + 2*(t0 + 12*b))
    int h  = blk & 7;
    int r  = blk >> 3;                 // 0..95
    int qg = r & 1;
    int t0 = (r >> 1) % NT0;
    int b  = r / (2 * NT0);
    int tid = threadIdx.x, wv = tid >> 6, lane = tid & 63;
    int l15 = lane & 15, kg = lane >> 4;

    int qbase = b * NQ + t0 * LL + qg * 32;
    const ushort* qp0 = qkv + (size_t)(qbase + l15) * 1536 + h * HD + kg * 8;
    const ushort* qp1 = qkv + (size_t)(qbase + 16 + l15) * 1536 + h * HD + kg * 8;
    bf16x8 qa0 = *(const bf16x8*)qp0;
    bf16x8 qa1 = *(const bf16x8*)(qp0 + 32);
    bf16x8 qb0 = *(const bf16x8*)qp1;
    bf16x8 qb1 = *(const bf16x8*)(qp1 + 32);

    f32x4 acc[2][4];
#pragma unroll
    for (int qf = 0; qf < 2; ++qf)
#pragma unroll
      for (int d = 0; d < 4; ++d) acc[qf][d] = (f32x4){0, 0, 0, 0};
    float Lacc[2] = {0.f, 0.f};
    ushort* Pt = (ushort*)smem + wv * 2432;  // 2 strips of 1216 (padded)

    const ushort* vctxb = vctxT + (size_t)h * HD * (BB * NCTX) + b * NCTX;
    int c = 0;
#pragma unroll 1
    for (int kt = 0; kt < TT; ++kt) {
      if (ctx_mask[b * TT + kt] == 0 || kt == t0 + 4) continue;
      if ((c++ & 3) == wv)
        attn_tile32(kctx + (size_t)(b * NCTX + kt * LL) * CC + h * HD, CC,
                    vctxb + kt * LL, BB * NCTX,
                    qa0, qa1, qb0, qb1, l15, kg, Pt, acc, Lacc);
    }
    if ((c & 3) == wv) {
      attn_tile32(qkv + (size_t)(b * NQ + t0 * LL) * 1536 + CC + h * HD, 1536,
                  vselfT + (size_t)h * HD * (BB * NQ) + b * NQ + t0 * LL, BB * NQ,
                  qa0, qa1, qb0, qb1, l15, kg, Pt, acc, Lacc);
    }

    float L0 = Lacc[0], L1 = Lacc[1];
    L0 += __shfl_xor(L0, 16, 64); L0 += __shfl_xor(L0, 32, 64);
    L1 += __shfl_xor(L1, 16, 64); L1 += __shfl_xor(L1, 32, 64);

    // merge: waves 1..3 publish (plain sums), wave 0 adds & writes
    __syncthreads();
    if (wv) {
      float* reg = smem + (size_t)(wv - 1) * 2176;  // 2048 acc + 128 L
#pragma unroll
      for (int qf = 0; qf < 2; ++qf)
#pragma unroll
        for (int d = 0; d < 4; ++d)
          *(f32x4*)(reg + (qf * 64 + lane) * 16 + d * 4) = acc[qf][d];
      reg[2048 + lane * 2]     = L0;
      reg[2048 + lane * 2 + 1] = L1;
    }
    __syncthreads();
    if (!wv) {
      float Ls[2] = {L0, L1};
      f32x4 o[2][4];
#pragma unroll
      for (int qf = 0; qf < 2; ++qf)
#pragma unroll
        for (int d = 0; d < 4; ++d) o[qf][d] = acc[qf][d];
#pragma unroll
      for (int j = 0; j < 3; ++j) {
        const float* reg = smem + (size_t)j * 2176;
        Ls[0] += reg[2048 + lane * 2];
        Ls[1] += reg[2048 + lane * 2 + 1];
#pragma unroll
        for (int qf = 0; qf < 2; ++qf)
#pragma unroll
          for (int d = 0; d < 4; ++d)
            o[qf][d] += *(const f32x4*)(reg + (qf * 64 + lane) * 16 + d * 4);
      }
#pragma unroll
      for (int qf = 0; qf < 2; ++qf) {
        float inv = 1.f / Ls[qf];
        int orow = qbase + qf * 16 + l15;
#pragma unroll
        for (int d = 0; d < 4; ++d) {
          ushort4 ov = { f2bf(o[qf][d][0] * inv), f2bf(o[qf][d][1] * inv),
                         f2bf(o[qf][d][2] * inv), f2bf(o[qf][d][3] * inv) };
          *(ushort4*)(aout + (size_t)orow * CC + h * HD + d * 16 + kg * 4) = ov;
        }
      }
    }
  }
  grid_bar(bar, 3);

  // ---- phase 4: proj (items 0..191; 48mt x 4nt of 64x128) ----
  if (blockIdx.x < 192) {
    int blk = blockIdx.x;
    gemm_body<64, 128, 2>(aout, pwb, nullptr, nullptr, out, proj_b,
                          blk % 48, blk / 48, 512, 0, lds);
  }
}

extern "C" void kernel_launch(void* const* d_in, const int* in_sizes, int n_in,
                              void* d_out, int out_size, void* d_ws, size_t ws_size,
                              hipStream_t stream) {
  const float* x        = (const float*)d_in[0];
  const float* x_ctx    = (const float*)d_in[1];
  const float* dx_ctx   = (const float*)d_in[2];
  const int*   ctx_mask = (const int*)d_in[3];
  const float* qkv_w    = (const float*)d_in[4];
  const float* k_w      = (const float*)d_in[5];
  const float* v_w      = (const float*)d_in[6];
  const float* proj_w   = (const float*)d_in[7];
  const float* proj_b   = (const float*)d_in[8];
  float* out = (float*)d_out;
  ushort* ws = (ushort*)d_ws;
  int* bar = (int*)(ws + 19398656);   // 8 B barrier state past live workspace

  hipMemsetAsync(bar, 0, 8, stream);  // stream-ordered, graph-capture legal
  fused_all<<<768, 256, 0, stream>>>(qkv_w, k_w, v_w, proj_w, x, x_ctx, dx_ctx,
                                     ctx_mask, ws, proj_b, out, bar);
}

// Round 9
// 129.208 us; speedup vs baseline: 4.0763x; 4.0763x over previous
//
#include <hip/hip_runtime.h>
#include <hip/hip_bf16.h>

typedef __attribute__((ext_vector_type(8))) short bf16x8;
typedef __attribute__((ext_vector_type(4))) float f32x4;

#define BB 4
#define TT 16
#define NT0 12
#define LL 64
#define CC 512
#define HH 8
#define HD 64
#define NQ (NT0*LL)       // 768 queries per batch
#define NCTX (TT*LL)      // 1024 cross keys per batch

#define GPTR(x) ((__attribute__((address_space(1))) void*)(x))
#define SPTR(x) ((__attribute__((address_space(3))) void*)(x))
// waitcnt imm: vmcnt(n) in [3:0] (n<=15 here), lgkmcnt=15 (no wait), expcnt=7 (no wait)
#define VMCNT(n) (((n) & 15) | (7u << 4) | (0xFu << 8))

// Session ledger (R11 baseline 137.1 -> R16 130.5 us):
//  R12 +: flash 768x256 blocks (uniform 3/CU)           134.6
//  R13 +: flash round-robin tile deal + XCD=h swizzle   130.8
//  R14 -: gemm3 128x64 tiles (barrier/staging overhead) 136.7 [reverted]
//  R15 -: gemm3 persistent work-steal (locality lost)   139.0 [reverted]
//  R16 +: flash Pt stride 72->76 (bank-conflict pad)    130.5 [best]
//  R17 -: cooperative fused kernel: launch fails under harness capture
//  R18 -: manual-barrier fused kernel: correct but 421us kernel (fence cost)
//  Fixed harness overhead in timed window: ~90-105 us (R8 measurement:
//  526.7 total - 421.7 kernel = 105 with a single kernel). Kernel budget ~40.

__device__ __forceinline__ float bf2f(ushort u) {
  union { unsigned int i; float f; } x; x.i = ((unsigned int)u) << 16; return x.f;
}
__device__ __forceinline__ ushort f2bf(float f) {
  union { float f; unsigned int i; } x; x.f = f;
  unsigned int r = x.i + 0x7fffu + ((x.i >> 16) & 1u);  // RNE
  return (ushort)(r >> 16);
}

// Convert f32 inputs -> bf16 workspace, layout [qkv_w|k_w|v_w|proj_w|x|x_ctx|dx_ctx].
// Skips x_ctx/dx_ctx frames whose ctx_mask is 0 (their kctx/vctx are never read).
__global__ __launch_bounds__(256) void cvt_all(const float* __restrict__ w0,
                                               const float* __restrict__ w1,
                                               const float* __restrict__ w2,
                                               const float* __restrict__ w3,
                                               const float* __restrict__ x,
                                               const float* __restrict__ xc,
                                               const float* __restrict__ dxc,
                                               const int* __restrict__ ctx_mask,
                                               ushort* __restrict__ dst) {
  long i = (long)blockIdx.x * 256 + threadIdx.x;  // float4 index, total 1835008
  const float* src; long off;
  if (i < 196608)       { src = w0;  off = 0; }
  else if (i < 262144)  { src = w1;  off = 196608; }
  else if (i < 327680)  { src = w2;  off = 262144; }
  else if (i < 393216)  { src = w3;  off = 327680; }
  else if (i < 786432)  { src = x;   off = 393216; }
  else if (i < 1310720) {
    int r = (int)((i - 786432) >> 7);            // row in (4096, 512)
    if (ctx_mask[(r >> 10) * TT + ((r >> 6) & 15)] == 0) return;
    src = xc;  off = 786432;
  } else {
    int r = (int)((i - 1310720) >> 7);
    if (ctx_mask[(r >> 10) * TT + ((r >> 6) & 15)] == 0) return;
    src = dxc; off = 1310720;
  }
  f32x4 v = *(const f32x4*)(src + (i - off) * 4);
  ushort4 o = { f2bf(v[0]), f2bf(v[1]), f2bf(v[2]), f2bf(v[3]) };
  *(ushort4*)(dst + i * 4) = o;
}

// ---------------------------------------------------------------------------
// MTxNTW-tile GEMM block body, BK=32, TRIPLE-BUFFER depth-2 (R10-proven):
// issue ks+2's loads, wait vmcnt(2L), raw s_barrier.
// ---------------------------------------------------------------------------
template<int MT, int NTW>
__device__ __forceinline__ void gemm_mac(const ushort* __restrict__ A,
                                         const ushort* __restrict__ W,
                                         int mt, int nt, ushort* lds,
                                         f32x4* acc) {
  constexpr int ASZ = MT * 32;         // A ushorts per buf
  constexpr int WSZ = NTW * 32;        // W ushorts per buf
  constexpr int BUF = ASZ + WSZ;       // buf stride in ushorts
  constexpr int L   = (MT == 128 ? 2 : 1) + (NTW == 128 ? 2 : 1);

  int t = threadIdx.x;
  int pa0 = t, pa1 = t + 256;
  int ra0 = pa0 >> 2, ra1 = pa1 >> 2;
  int ca0 = (pa0 & 3) ^ ((ra0 >> 1) & 3);
  int ca1 = (pa1 & 3) ^ ((ra1 >> 1) & 3);
  const ushort* ga0 = A + (size_t)(mt * MT + ra0) * 512 + ca0 * 8;
  const ushort* ga1 = A + (size_t)(mt * MT + ra1) * 512 + ca1 * 8;
  const ushort* gw0 = W + (size_t)(nt * NTW + ra0) * 512 + ca0 * 8;
  const ushort* gw1 = W + (size_t)(nt * NTW + ra1) * 512 + ca1 * 8;

  int lane = t & 63, l15 = lane & 15, kg = lane >> 4;
  int wv = t >> 6;
  int mh = (wv >> 1) * (MT / 2), nh = (wv & 1) * (NTW / 2);
  int swz = kg ^ ((l15 >> 1) & 3);
  int faoff = (mh + l15) * 32 + swz * 8;
  int fwoff = (nh + l15) * 32 + swz * 8;

  auto stage = [&](int ks, int bb) {
    int ko = ks * 32;
    __builtin_amdgcn_global_load_lds(GPTR(ga0 + ko), SPTR(lds + bb + pa0 * 8), 16, 0, 0);
    if (MT == 128)
      __builtin_amdgcn_global_load_lds(GPTR(ga1 + ko), SPTR(lds + bb + pa1 * 8), 16, 0, 0);
    __builtin_amdgcn_global_load_lds(GPTR(gw0 + ko), SPTR(lds + bb + ASZ + pa0 * 8), 16, 0, 0);
    if (NTW == 128)
      __builtin_amdgcn_global_load_lds(GPTR(gw1 + ko), SPTR(lds + bb + ASZ + pa1 * 8), 16, 0, 0);
  };

  stage(0, 0);
  stage(1, BUF);

#pragma unroll
  for (int ks = 0; ks < 16; ++ks) {
    int cur = (ks % 3) * BUF;
    if (ks < 14) {
      stage(ks + 2, ((ks + 2) % 3) * BUF);
      __builtin_amdgcn_s_waitcnt(VMCNT(2 * L));
    } else if (ks == 14) {
      __builtin_amdgcn_s_waitcnt(VMCNT(L));
    } else {
      __builtin_amdgcn_s_waitcnt(VMCNT(0));
    }
    asm volatile("" ::: "memory");
    __builtin_amdgcn_s_barrier();
    asm volatile("" ::: "memory");

    const ushort* fa = lds + cur + faoff;
    const ushort* fw = lds + cur + ASZ + fwoff;
    bf16x8 af[MT / 32], wf[NTW / 32];
#pragma unroll
    for (int i = 0; i < MT / 32; ++i) af[i] = *(const bf16x8*)(fa + i * 512);
#pragma unroll
    for (int i = 0; i < NTW / 32; ++i) wf[i] = *(const bf16x8*)(fw + i * 512);
#pragma unroll
    for (int mi = 0; mi < MT / 32; ++mi)
#pragma unroll
      for (int ni = 0; ni < NTW / 32; ++ni)
        acc[mi * (NTW / 32) + ni] =
            __builtin_amdgcn_mfma_f32_16x16x32_bf16(af[mi], wf[ni], acc[mi * (NTW / 32) + ni], 0, 0, 0);

    asm volatile("" ::: "memory");
    __builtin_amdgcn_s_barrier();
    asm volatile("" ::: "memory");
  }
}

// OUTMODE 0: C bf16 row-major [*,N]. 1: CT bf16 transposed CT[col*TM+row]
// (CT may be pre-offset). 2: Cf f32 row-major + bias.
template<int MT, int NTW, int OUTMODE>
__device__ __forceinline__ void gemm_body(const ushort* __restrict__ A,
                                          const ushort* __restrict__ W,
                                          ushort* __restrict__ C,
                                          ushort* __restrict__ CT,
                                          float* __restrict__ Cf,
                                          const float* __restrict__ bias,
                                          int mt, int nt, int N, long TM,
                                          ushort* lds) {
  f32x4 acc[(MT / 32) * (NTW / 32)];
#pragma unroll
  for (int i = 0; i < (MT / 32) * (NTW / 32); ++i) acc[i] = (f32x4){0, 0, 0, 0};
  gemm_mac<MT, NTW>(A, W, mt, nt, lds, acc);

  int lane = threadIdx.x & 63, l15 = lane & 15, kg = lane >> 4;
  int wv = threadIdx.x >> 6;
  int Rw = mt * MT + (wv >> 1) * (MT / 2);
  int Cw = nt * NTW + (wv & 1) * (NTW / 2);
#pragma unroll
  for (int mi = 0; mi < MT / 32; ++mi) {
    int row = Rw + mi * 16 + kg * 4;
#pragma unroll
    for (int ni = 0; ni < NTW / 32; ++ni) {
      f32x4 v = acc[mi * (NTW / 32) + ni];
      int col = Cw + ni * 16 + l15;
      if (OUTMODE == 0) {
#pragma unroll
        for (int r = 0; r < 4; ++r) C[(size_t)(row + r) * N + col] = f2bf(v[r]);
      } else if (OUTMODE == 1) {
        ushort4 o = { f2bf(v[0]), f2bf(v[1]), f2bf(v[2]), f2bf(v[3]) };
        *(ushort4*)(CT + (long)col * TM + row) = o;
      } else {
        float bv = bias[col];
#pragma unroll
        for (int r = 0; r < 4; ++r) Cf[(size_t)(row + r) * N + col] = v[r] + bv;
      }
    }
  }
}

// Fused input GEMMs (R13-proven static config). blocks [0,288): qkv =
// x@qkv_w.T (24m x 12n tiles; n-tiles >=8 are self-V cols -> transposed into
// vselfT). [288,416): kctx (32x4). [416,544): vctx^T (32x4). kctx/vctx tiles
// whose BOTH covered frames are masked exit before staging.
// mt fast and 24/32 = 0 mod 8 -> A-panel reuse is XCD-local.
__global__ __launch_bounds__(256) void gemm3(const ushort* __restrict__ xb,
                                             const ushort* __restrict__ dxb,
                                             const ushort* __restrict__ xcb,
                                             const ushort* __restrict__ qkvwb,
                                             const ushort* __restrict__ kwb,
                                             const ushort* __restrict__ vwb,
                                             const int* __restrict__ ctx_mask,
                                             ushort* __restrict__ qkv,
                                             ushort* __restrict__ vselfT,
                                             ushort* __restrict__ kctx,
                                             ushort* __restrict__ vctxT) {
  __shared__ ushort lds[24576];   // 3 bufs x (A 8KB + W 8KB) = 48 KB
  int blk = blockIdx.x;
  if (blk < 288) {
    int mt = blk % 24, nt = blk / 24;
    if (nt < 8)
      gemm_body<128, 128, 0>(xb, qkvwb, qkv, nullptr, nullptr, nullptr, mt, nt, 1536, 0, lds);
    else
      gemm_body<128, 128, 1>(xb, qkvwb, nullptr, vselfT - (size_t)1024 * 3072, nullptr, nullptr,
                             mt, nt, 1536, 3072, lds);
  } else if (blk < 416) {
    int r = blk - 288;
    int mt = r % 32, nt = r / 32;
    int bb = mt >> 3, f0 = (mt & 7) << 1;
    if (ctx_mask[bb * TT + f0] == 0 && ctx_mask[bb * TT + f0 + 1] == 0) return;
    gemm_body<128, 128, 0>(dxb, kwb, kctx, nullptr, nullptr, nullptr, mt, nt, 512, 0, lds);
  } else {
    int r = blk - 416;
    int mt = r % 32, nt = r / 32;
    int bb = mt >> 3, f0 = (mt & 7) << 1;
    if (ctx_mask[bb * TT + f0] == 0 && ctx_mask[bb * TT + f0 + 1] == 0) return;
    gemm_body<128, 128, 1>(xcb, vwb, nullptr, vctxT, nullptr, nullptr, mt, nt, 512, 4096, lds);
  }
}

// proj: 64-row tiles -> 192 blocks (48 mt x 4 nt).
__global__ __launch_bounds__(256) void gemm_proj(const ushort* __restrict__ aout,
                                                 const ushort* __restrict__ pwb,
                                                 const float* __restrict__ bias,
                                                 float* __restrict__ out) {
  __shared__ ushort lds[18432];   // 3 bufs x (A 4KB + W 8KB) = 36 KB
  int blk = blockIdx.x;
  gemm_body<64, 128, 2>(aout, pwb, nullptr, nullptr, out, bias, blk % 48, blk / 48, 512, 0, lds);
}

// One attention tile for a 32-query wave: one K/V fragment stream feeds TWO
// 16-query S^T/PV chains (halves K/V L2 traffic per query). [R11-proven]
// R16: Pt strip stride 72 -> 76 ushorts (38 dwords = 6 mod 32, coprime bank
// spread; conflicts were 1.1M cycles/dispatch at stride 72).
__device__ __forceinline__ void attn_tile32(const ushort* __restrict__ kbase, int kstr,
                                            const ushort* __restrict__ vtb, int vtN,
                                            bf16x8 qa0, bf16x8 qa1,
                                            bf16x8 qb0, bf16x8 qb1,
                                            int l15, int kg,
                                            ushort* __restrict__ Pt,
                                            f32x4 (*acc)[4], float* Lacc) {
  f32x4 s[2][4];
#pragma unroll
  for (int st = 0; st < 4; ++st) {
    const ushort* kp = kbase + (size_t)(st * 16 + l15) * kstr + kg * 8;
    bf16x8 k0 = *(const bf16x8*)kp;
    bf16x8 k1 = *(const bf16x8*)(kp + 32);
    f32x4 z0 = {0, 0, 0, 0}, z1 = {0, 0, 0, 0};
    z0 = __builtin_amdgcn_mfma_f32_16x16x32_bf16(k0, qa0, z0, 0, 0, 0);
    z0 = __builtin_amdgcn_mfma_f32_16x16x32_bf16(k1, qa1, z0, 0, 0, 0);
    z1 = __builtin_amdgcn_mfma_f32_16x16x32_bf16(k0, qb0, z1, 0, 0, 0);
    z1 = __builtin_amdgcn_mfma_f32_16x16x32_bf16(k1, qb1, z1, 0, 0, 0);
    s[0][st] = z0;
    s[1][st] = z1;
  }
#pragma unroll
  for (int qf = 0; qf < 2; ++qf) {
#pragma unroll
    for (int st = 0; st < 4; ++st) {
      float p0 = __builtin_exp2f(fmaf(s[qf][st][0], 0.18033688f, -23.0831206f));
      float p1 = __builtin_exp2f(fmaf(s[qf][st][1], 0.18033688f, -23.0831206f));
      float p2 = __builtin_exp2f(fmaf(s[qf][st][2], 0.18033688f, -23.0831206f));
      float p3 = __builtin_exp2f(fmaf(s[qf][st][3], 0.18033688f, -23.0831206f));
      Lacc[qf] += (p0 + p1) + (p2 + p3);
      ushort4 pk = { f2bf(p0), f2bf(p1), f2bf(p2), f2bf(p3) };
      *(ushort4*)(Pt + qf * 1216 + l15 * 76 + st * 16 + kg * 4) = pk;
    }
  }
#pragma unroll
  for (int kc = 0; kc < 2; ++kc) {
    bf16x8 pb0 = *(const bf16x8*)(Pt + l15 * 76 + kc * 32 + kg * 8);
    bf16x8 pb1 = *(const bf16x8*)(Pt + 1216 + l15 * 76 + kc * 32 + kg * 8);
#pragma unroll
    for (int d = 0; d < 4; ++d) {
      const ushort* vp = vtb + (size_t)(d * 16 + l15) * vtN + kc * 32 + kg * 8;
      bf16x8 vf = *(const bf16x8*)vp;
      acc[0][d] = __builtin_amdgcn_mfma_f32_16x16x32_bf16(vf, pb0, acc[0][d], 0, 0, 0);
      acc[1][d] = __builtin_amdgcn_mfma_f32_16x16x32_bf16(vf, pb1, acc[1][d], 0, 0, 0);
    }
  }
}

// Flash attention, fixed-M streaming softmax, 32-query waves.
// R13 [proven]: round-robin tile deal across the 4 waves; XCD = h (L2-local
// K/V). R16 [proven]: padded Pt strips (76-ushort rows, 1216/strip).
__global__ __launch_bounds__(256, 4) void flash_attn(const ushort* __restrict__ qkv,
                                                     const ushort* __restrict__ kctx,
                                                     const ushort* __restrict__ vctxT,
                                                     const ushort* __restrict__ vselfT,
                                                     const int* __restrict__ ctx_mask,
                                                     ushort* __restrict__ aout) {
  __shared__ float smem[6528];       // 26.1 KB; Pt strips (19.5 KB) alias low part
  int blk = blockIdx.x;              // h + 8*(qg + 2*(t0 + 12*b))
  int h  = blk & 7;
  int r  = blk >> 3;                 // 0..95
  int qg = r & 1;
  int t0 = (r >> 1) % NT0;
  int b  = r / (2 * NT0);
  int tid = threadIdx.x, wv = tid >> 6, lane = tid & 63;
  int l15 = lane & 15, kg = lane >> 4;

  int qbase = b * NQ + t0 * LL + qg * 32;
  const ushort* qp0 = qkv + (size_t)(qbase + l15) * 1536 + h * HD + kg * 8;
  const ushort* qp1 = qkv + (size_t)(qbase + 16 + l15) * 1536 + h * HD + kg * 8;
  bf16x8 qa0 = *(const bf16x8*)qp0;
  bf16x8 qa1 = *(const bf16x8*)(qp0 + 32);
  bf16x8 qb0 = *(const bf16x8*)qp1;
  bf16x8 qb1 = *(const bf16x8*)(qp1 + 32);

  f32x4 acc[2][4];
#pragma unroll
  for (int qf = 0; qf < 2; ++qf)
#pragma unroll
    for (int d = 0; d < 4; ++d) acc[qf][d] = (f32x4){0, 0, 0, 0};
  float Lacc[2] = {0.f, 0.f};
  ushort* Pt = (ushort*)smem + wv * 2432;  // 2 strips of 1216 (padded, single-buffered)

  // Round-robin deal of eligible context tiles across the 4 waves.
  const ushort* vctxb = vctxT + (size_t)h * HD * (BB * NCTX) + b * NCTX;
  int c = 0;
#pragma unroll 1
  for (int kt = 0; kt < TT; ++kt) {
    if (ctx_mask[b * TT + kt] == 0 || kt == t0 + 4) continue;
    if ((c++ & 3) == wv)
      attn_tile32(kctx + (size_t)(b * NCTX + kt * LL) * CC + h * HD, CC,
                  vctxb + kt * LL, BB * NCTX,
                  qa0, qa1, qb0, qb1, l15, kg, Pt, acc, Lacc);
  }
  // Self tile goes to the next wave in the deal (always present -> L > 0).
  if ((c & 3) == wv) {
    attn_tile32(qkv + (size_t)(b * NQ + t0 * LL) * 1536 + CC + h * HD, 1536,
                vselfT + (size_t)h * HD * (BB * NQ) + b * NQ + t0 * LL, BB * NQ,
                qa0, qa1, qb0, qb1, l15, kg, Pt, acc, Lacc);
  }

  float L0 = Lacc[0], L1 = Lacc[1];
  L0 += __shfl_xor(L0, 16, 64); L0 += __shfl_xor(L0, 32, 64);
  L1 += __shfl_xor(L1, 16, 64); L1 += __shfl_xor(L1, 32, 64);

  // ---- merge: waves 1..3 publish (plain sums), wave 0 adds & writes ----
  __syncthreads();
  if (wv) {
    float* reg = smem + (size_t)(wv - 1) * 2176;  // 2048 acc + 128 L
#pragma unroll
    for (int qf = 0; qf < 2; ++qf)
#pragma unroll
      for (int d = 0; d < 4; ++d)
        *(f32x4*)(reg + (qf * 64 + lane) * 16 + d * 4) = acc[qf][d];
    reg[2048 + lane * 2]     = L0;
    reg[2048 + lane * 2 + 1] = L1;
  }
  __syncthreads();
  if (!wv) {
    float Ls[2] = {L0, L1};
    f32x4 o[2][4];
#pragma unroll
    for (int qf = 0; qf < 2; ++qf)
#pragma unroll
      for (int d = 0; d < 4; ++d) o[qf][d] = acc[qf][d];
#pragma unroll
    for (int j = 0; j < 3; ++j) {
      const float* reg = smem + (size_t)j * 2176;
      Ls[0] += reg[2048 + lane * 2];
      Ls[1] += reg[2048 + lane * 2 + 1];
#pragma unroll
      for (int qf = 0; qf < 2; ++qf)
#pragma unroll
        for (int d = 0; d < 4; ++d)
          o[qf][d] += *(const f32x4*)(reg + (qf * 64 + lane) * 16 + d * 4);
    }
#pragma unroll
    for (int qf = 0; qf < 2; ++qf) {
      float inv = 1.f / Ls[qf];
      int orow = qbase + qf * 16 + l15;
#pragma unroll
      for (int d = 0; d < 4; ++d) {
        ushort4 ov = { f2bf(o[qf][d][0] * inv), f2bf(o[qf][d][1] * inv),
                       f2bf(o[qf][d][2] * inv), f2bf(o[qf][d][3] * inv) };
        *(ushort4*)(aout + (size_t)orow * CC + h * HD + d * 16 + kg * 4) = ov;
      }
    }
  }
}

extern "C" void kernel_launch(void* const* d_in, const int* in_sizes, int n_in,
                              void* d_out, int out_size, void* d_ws, size_t ws_size,
                              hipStream_t stream) {
  const float* x        = (const float*)d_in[0];
  const float* x_ctx    = (const float*)d_in[1];
  const float* dx_ctx   = (const float*)d_in[2];
  const int*   ctx_mask = (const int*)d_in[3];
  const float* qkv_w    = (const float*)d_in[4];
  const float* k_w      = (const float*)d_in[5];
  const float* v_w      = (const float*)d_in[6];
  const float* proj_w   = (const float*)d_in[7];
  const float* proj_b   = (const float*)d_in[8];
  float* out = (float*)d_out;

  ushort* ws = (ushort*)d_ws;   // element offsets (bf16)
  ushort* qkvwb  = ws;                    //  786432
  ushort* kwb    = ws + 786432;           //  262144
  ushort* vwb    = ws + 1048576;          //  262144
  ushort* pwb    = ws + 1310720;          //  262144
  ushort* xb     = ws + 1572864;          // 1572864  (3072x512)
  ushort* xcb    = ws + 3145728;          // 2097152  (4096x512)
  ushort* dxb    = ws + 5242880;          // 2097152  (4096x512)
  ushort* qkv    = ws + 7340032;          // 3072x1536
  ushort* kctx   = ws + 12058624;         // 4096x512
  ushort* vctxT  = ws + 14155776;         // 512x4096
  ushort* vselfT = ws + 16252928;         // 512x3072
  ushort* aout   = ws + 17825792;         // 3072x512  (end 19398656 el = 38.8MB)

  cvt_all<<<7168, 256, 0, stream>>>(qkv_w, k_w, v_w, proj_w, x, x_ctx, dx_ctx,
                                    ctx_mask, ws);
  gemm3<<<544, 256, 0, stream>>>(xb, dxb, xcb, qkvwb, kwb, vwb, ctx_mask,
                                 qkv, vselfT, kctx, vctxT);
  flash_attn<<<768, 256, 0, stream>>>(qkv, kctx, vctxT, vselfT, ctx_mask, aout);
  gemm_proj<<<192, 256, 0, stream>>>(aout, pwb, proj_b, out);
}